// Round 6
// baseline (146.733 us; speedup 1.0000x reference)
//
#include <hip/hip_runtime.h>

// Shapes fixed by the reference: B=4, N=M=384, D=256.
#define DD 256
#define NN 384
#define BB 4
#define BN (BB * NN)         // 1536
#define MSPLIT 8
#define MCHUNK (NN / MSPLIT) // 48
#define ROWS 8               // n-rows per mhsa block
#define PSTRIDE (BN * DD)    // one partial plane

// tanh(s) = 1 - 2/(exp2(2*log2e*s)+1). K pre-scaled by 2*log2e; mask adds
// -1e9*2log2e in the exp2 domain -> E=0 -> rcp(1)=1 -> contribution -v exact.
constexpr float TWO_LOG2E = 2.8853900817779268f;
constexpr float MASK_X    = -1.0e9f * 2.8853900817779268f;

// ---------------------------------------------------------------------------
// Projections. grid (BN/8, 3), block 256 = 4 waves; wave w owns rows
// {blockIdx.x*8 + 2w, +2w+1} across ALL k (no k-split -> no LDS, no barrier,
// no cross-wave reduce). W streamed coalesced dwordx4 (4 waves share via L1);
// x read as wave-uniform broadcast float4 from global (VMEM, in-order vmcnt;
// R3 showed scalar s_load serializes on out-of-order lgkmcnt).
// ---------------------------------------------------------------------------
__global__ __launch_bounds__(256) void proj_kernel(
    const float* __restrict__ q,  const float* __restrict__ k,  const float* __restrict__ v,
    const float* __restrict__ Wq, const float* __restrict__ Wk, const float* __restrict__ Wv,
    const float* __restrict__ bq, const float* __restrict__ bk, const float* __restrict__ bv,
    float* __restrict__ Qout, float* __restrict__ KVout)
{
    const int tid  = threadIdx.x;
    const int lane = tid & 63;
    const int wv   = tid >> 6;
    const int row  = blockIdx.x * 8 + wv * 2;   // this wave: rows row, row+1
    const int which = blockIdx.y;

    const float* X; const float* W; const float* bias; float scale; float* out; int ostride;
    if (which == 0)      { X = q; W = Wq; bias = bq; scale = 1.0f;      out = Qout;      ostride = 1; }
    else if (which == 1) { X = k; W = Wk; bias = bk; scale = TWO_LOG2E; out = KVout;     ostride = 2; }
    else                 { X = v; W = Wv; bias = bv; scale = 1.0f;      out = KVout + 1; ostride = 2; }

    const float* X0 = X + (size_t)row * DD;
    const float* X1 = X0 + DD;
    const float* Wp = W + lane * 4;             // W[k][lane*4..+3], coalesced

    float4 a0 = make_float4(0.f, 0.f, 0.f, 0.f);
    float4 a1 = make_float4(0.f, 0.f, 0.f, 0.f);

    #pragma unroll 2
    for (int kk = 0; kk < DD; kk += 4) {
        const float4 x0 = *reinterpret_cast<const float4*>(X0 + kk);  // broadcast (L1)
        const float4 x1 = *reinterpret_cast<const float4*>(X1 + kk);  // broadcast
        const float4 w0 = *reinterpret_cast<const float4*>(Wp + (size_t)(kk + 0) * DD);
        const float4 w1 = *reinterpret_cast<const float4*>(Wp + (size_t)(kk + 1) * DD);
        const float4 w2 = *reinterpret_cast<const float4*>(Wp + (size_t)(kk + 2) * DD);
        const float4 w3 = *reinterpret_cast<const float4*>(Wp + (size_t)(kk + 3) * DD);

        a0.x = fmaf(x0.x, w0.x, a0.x); a0.y = fmaf(x0.x, w0.y, a0.y);
        a0.z = fmaf(x0.x, w0.z, a0.z); a0.w = fmaf(x0.x, w0.w, a0.w);
        a1.x = fmaf(x1.x, w0.x, a1.x); a1.y = fmaf(x1.x, w0.y, a1.y);
        a1.z = fmaf(x1.x, w0.z, a1.z); a1.w = fmaf(x1.x, w0.w, a1.w);

        a0.x = fmaf(x0.y, w1.x, a0.x); a0.y = fmaf(x0.y, w1.y, a0.y);
        a0.z = fmaf(x0.y, w1.z, a0.z); a0.w = fmaf(x0.y, w1.w, a0.w);
        a1.x = fmaf(x1.y, w1.x, a1.x); a1.y = fmaf(x1.y, w1.y, a1.y);
        a1.z = fmaf(x1.y, w1.z, a1.z); a1.w = fmaf(x1.y, w1.w, a1.w);

        a0.x = fmaf(x0.z, w2.x, a0.x); a0.y = fmaf(x0.z, w2.y, a0.y);
        a0.z = fmaf(x0.z, w2.z, a0.z); a0.w = fmaf(x0.z, w2.w, a0.w);
        a1.x = fmaf(x1.z, w2.x, a1.x); a1.y = fmaf(x1.z, w2.y, a1.y);
        a1.z = fmaf(x1.z, w2.z, a1.z); a1.w = fmaf(x1.z, w2.w, a1.w);

        a0.x = fmaf(x0.w, w3.x, a0.x); a0.y = fmaf(x0.w, w3.y, a0.y);
        a0.z = fmaf(x0.w, w3.z, a0.z); a0.w = fmaf(x0.w, w3.w, a0.w);
        a1.x = fmaf(x1.w, w3.x, a1.x); a1.y = fmaf(x1.w, w3.y, a1.y);
        a1.z = fmaf(x1.w, w3.z, a1.z); a1.w = fmaf(x1.w, w3.w, a1.w);
    }

    const float4 bb = *reinterpret_cast<const float4*>(bias + lane * 4);
    const float r0x = (a0.x + bb.x) * scale, r0y = (a0.y + bb.y) * scale;
    const float r0z = (a0.z + bb.z) * scale, r0w = (a0.w + bb.w) * scale;
    const float r1x = (a1.x + bb.x) * scale, r1y = (a1.y + bb.y) * scale;
    const float r1z = (a1.z + bb.z) * scale, r1w = (a1.w + bb.w) * scale;

    if (ostride == 1) {     // Q: contiguous float4 store
        *reinterpret_cast<float4*>(out + (size_t)row * DD + lane * 4)
            = make_float4(r0x, r0y, r0z, r0w);
        *reinterpret_cast<float4*>(out + (size_t)(row + 1) * DD + lane * 4)
            = make_float4(r1x, r1y, r1z, r1w);
    } else {                // K'/V: interleaved, stride-2 dword stores
        float* o0 = out + ((size_t)row * DD + lane * 4) * 2;
        float* o1 = out + ((size_t)(row + 1) * DD + lane * 4) * 2;
        o0[0] = r0x; o0[2] = r0y; o0[4] = r0z; o0[6] = r0w;
        o1[0] = r1x; o1[2] = r1y; o1[4] = r1z; o1[6] = r1w;
    }
}

// ---------------------------------------------------------------------------
// Fused tanh-contraction. grid (NN/ROWS, BB, MSPLIT) = (48,4,8) = 1536 blocks
// (6/CU, 6 waves/SIMD), block 256 (tid = d). 8 n-rows per block: shared per-m
// work (kv load, t2, vsum, 2 mask b128) amortized over 8 tanh rows; KV load
// count halved vs R5. Named double-buffer regs (R4: arrays+conditional refill
// spilled 149 MB). Overreads past the chunk stay inside ws -> harmless.
// ---------------------------------------------------------------------------
__global__ __launch_bounds__(256) void mhsa_kernel(
    const float* __restrict__ Q, const float* __restrict__ KV,
    const int* __restrict__ mask, float* __restrict__ outp)
{
    const int tid = threadIdx.x;         // d
    const int b   = blockIdx.y;
    const int n0  = blockIdx.x * ROWS;
    const int m0  = blockIdx.z * MCHUNK;

    __shared__ float mf[MCHUNK][ROWS];   // additive exp2-domain mask, 1.5 KB
    for (int idx = tid; idx < MCHUNK * ROWS; idx += 256) {
        const int m = idx % MCHUNK;      // consecutive tid -> consecutive m
        const int j = idx / MCHUNK;
        mf[m][j] = mask[(size_t)(b * NN + n0 + j) * NN + (m0 + m)] ? MASK_X : 0.0f;
    }
    __syncthreads();

    const float* Qp = Q + (size_t)(b * NN + n0) * DD + tid;
    float qv0 = Qp[0 * DD], qv1 = Qp[1 * DD], qv2 = Qp[2 * DD], qv3 = Qp[3 * DD];
    float qv4 = Qp[4 * DD], qv5 = Qp[5 * DD], qv6 = Qp[6 * DD], qv7 = Qp[7 * DD];

    const float2* kvp = reinterpret_cast<const float2*>(KV)
                      + (size_t)b * NN * DD + (size_t)m0 * DD + tid;

    float acc0 = 0.f, acc1 = 0.f, acc2 = 0.f, acc3 = 0.f;
    float acc4 = 0.f, acc5 = 0.f, acc6 = 0.f, acc7 = 0.f, vsum = 0.f;

#define TANH1(ACC, XV, T2) \
    ACC = fmaf(T2, __builtin_amdgcn_rcpf(__builtin_amdgcn_exp2f(XV) + 1.0f), ACC);

#define COMP(KVV, MLOC)                                                        \
    {                                                                          \
        const float4 ma = *reinterpret_cast<const float4*>(&mf[MLOC][0]);      \
        const float4 mb = *reinterpret_cast<const float4*>(&mf[MLOC][4]);      \
        const float kk = (KVV).x, vv = (KVV).y;                                \
        const float t2 = -2.0f * vv;                                           \
        vsum += vv;                                                            \
        TANH1(acc0, fmaf(qv0, kk, ma.x), t2)                                   \
        TANH1(acc1, fmaf(qv1, kk, ma.y), t2)                                   \
        TANH1(acc2, fmaf(qv2, kk, ma.z), t2)                                   \
        TANH1(acc3, fmaf(qv3, kk, ma.w), t2)                                   \
        TANH1(acc4, fmaf(qv4, kk, mb.x), t2)                                   \
        TANH1(acc5, fmaf(qv5, kk, mb.y), t2)                                   \
        TANH1(acc6, fmaf(qv6, kk, mb.z), t2)                                   \
        TANH1(acc7, fmaf(qv7, kk, mb.w), t2)                                   \
    }

#define LOADG(B0, B1, B2, B3, M0)                \
    B0 = kvp[(size_t)((M0) + 0) * DD];           \
    B1 = kvp[(size_t)((M0) + 1) * DD];           \
    B2 = kvp[(size_t)((M0) + 2) * DD];           \
    B3 = kvp[(size_t)((M0) + 3) * DD];

    float2 A0, A1, A2, A3, B0, B1, B2, B3;
    LOADG(A0, A1, A2, A3, 0)
    LOADG(B0, B1, B2, B3, 4)

    for (int mg = 0; mg < MCHUNK; mg += 8) {
        COMP(A0, mg + 0) COMP(A1, mg + 1) COMP(A2, mg + 2) COMP(A3, mg + 3)
        LOADG(A0, A1, A2, A3, mg + 8)    // last iter overreads m 48..51: in ws, unused
        COMP(B0, mg + 4) COMP(B1, mg + 5) COMP(B2, mg + 6) COMP(B3, mg + 7)
        LOADG(B0, B1, B2, B3, mg + 12)   // last iter overreads m 52..55: in ws, unused
    }
#undef COMP
#undef TANH1
#undef LOADG

    float* po = outp + (size_t)blockIdx.z * PSTRIDE + (size_t)(b * NN + n0) * DD + tid;
    po[0 * DD] = acc0 + vsum; po[1 * DD] = acc1 + vsum;
    po[2 * DD] = acc2 + vsum; po[3 * DD] = acc3 + vsum;
    po[4 * DD] = acc4 + vsum; po[5 * DD] = acc5 + vsum;
    po[6 * DD] = acc6 + vsum; po[7 * DD] = acc7 + vsum;
}

// Sum the MSPLIT partial planes. grid BN*DD/256 = 1536 blocks.
__global__ __launch_bounds__(256) void reduce8_kernel(
    const float* __restrict__ part, float* __restrict__ out)
{
    const int i = blockIdx.x * 256 + threadIdx.x;
    float s0 = part[i + 0 * PSTRIDE] + part[i + 1 * PSTRIDE];
    float s1 = part[i + 2 * PSTRIDE] + part[i + 3 * PSTRIDE];
    float s2 = part[i + 4 * PSTRIDE] + part[i + 5 * PSTRIDE];
    float s3 = part[i + 6 * PSTRIDE] + part[i + 7 * PSTRIDE];
    out[i] = (s0 + s1) + (s2 + s3);
}

extern "C" void kernel_launch(void* const* d_in, const int* in_sizes, int n_in,
                              void* d_out, int out_size, void* d_ws, size_t ws_size,
                              hipStream_t stream) {
    const float* q    = (const float*)d_in[0];
    const float* k    = (const float*)d_in[1];
    const float* v    = (const float*)d_in[2];
    const int*   mask = (const int*)  d_in[3];
    const float* Wq   = (const float*)d_in[4];
    const float* bq   = (const float*)d_in[5];
    const float* Wk   = (const float*)d_in[6];
    const float* bk   = (const float*)d_in[7];
    const float* Wv   = (const float*)d_in[8];
    const float* bv   = (const float*)d_in[9];
    float* out = (float*)d_out;

    float* Qws   = (float*)d_ws;                 // BN*DD floats      (1.57 MB)
    float* KVws  = Qws  + (size_t)BN * DD;       // BN*DD float2s     (3.15 MB)
    float* Pws   = KVws + (size_t)2 * BN * DD;   // MSPLIT planes     (12.6 MB)
                                                 // (KV overread lands in Pws: safe)

    dim3 g1(BN / 8, 3);
    proj_kernel<<<g1, 256, 0, stream>>>(q, k, v, Wq, Wk, Wv, bq, bk, bv, Qws, KVws);

    dim3 g2(NN / ROWS, BB, MSPLIT);
    mhsa_kernel<<<g2, 256, 0, stream>>>(Qws, KVws, mask, Pws);

    reduce8_kernel<<<dim3(BN * DD / 256), 256, 0, stream>>>(Pws, out);
}